// Round 1
// baseline (4987.665 us; speedup 1.0000x reference)
//
#include <hip/hip_runtime.h>
#include <hip/hip_bf16.h>

typedef unsigned short u16;
typedef __attribute__((ext_vector_type(4))) float f32x4;
typedef __attribute__((ext_vector_type(8))) short short8;
typedef __attribute__((ext_vector_type(8))) __bf16 bf16x8;

#define TBN ((size_t)65536)  // T*B

// frag-layout offsets in u16 elements inside d_ws
#define OFF_WIH  0         // [3 gates][13 ct][7 ks][512]
#define OFF_WHH  139776
#define OFF_WP1  279552    // [13][7][512]
#define OFF_WQ1D 326144
#define OFF_WP2  372736    // [4][7][512]
#define OFF_WQ2  387072
#define OFF_WQ1E 401408    // [32 ks][13 ct][512]
#define FRAG_TOTAL 614400

__device__ __forceinline__ u16 f2bf(float f) {
  unsigned u = __builtin_bit_cast(unsigned, f);
  unsigned r = u + 0x7fffu + ((u >> 16) & 1u);
  return (u16)(r >> 16);
}

__device__ __forceinline__ f32x4 mfma16(short8 a, short8 b, f32x4 c) {
  return __builtin_amdgcn_mfma_f32_16x16x32_bf16(
      __builtin_bit_cast(bf16x8, a), __builtin_bit_cast(bf16x8, b), c, 0, 0, 0);
}

// ---------------- P0: pack weights into MFMA B-fragment order (bf16) --------
__global__ __launch_bounds__(512) void prep_frags(
    const float* __restrict__ Wih, const float* __restrict__ Whh,
    const float* __restrict__ Wp1, const float* __restrict__ Wq1,
    const float* __restrict__ Wp2, const float* __restrict__ Wq2,
    u16* __restrict__ ws) {
  int id = blockIdx.x * 512 + threadIdx.x;
  float v = 0.f;
  if (id < 279552) {                       // WIH / WHH  (K=200, N=3x200)
    const float* W = (id < 139776) ? Wih : Whh;
    int idx2 = (id < 139776) ? id : id - 139776;
    int fb = idx2 >> 9, r = idx2 & 511, l = r >> 3, i = r & 7;
    int g = fb / 91, rem = fb % 91, ct = rem / 7, ks = rem % 7;
    int k = ks*32 + ((l >> 4) << 3) + i;
    int col = ct*16 + (l & 15);
    if (k < 200 && col < 200) v = W[k*600 + g*200 + col];
  } else if (id < 372736) {                // WP1 / WQ1D  (K=200, N=200)
    const float* W = (id < 326144) ? Wp1 : Wq1;
    int idx2 = (id < 326144) ? id - 279552 : id - 326144;
    int fb = idx2 >> 9, r = idx2 & 511, l = r >> 3, i = r & 7;
    int ct = fb / 7, ks = fb % 7;
    int k = ks*32 + ((l >> 4) << 3) + i;
    int col = ct*16 + (l & 15);
    if (k < 200 && col < 200) v = W[k*200 + col];
  } else if (id < 401408) {                // WP2 / WQ2  (K=200, N=60)
    const float* W = (id < 387072) ? Wp2 : Wq2;
    int idx2 = (id < 387072) ? id - 372736 : id - 387072;
    int fb = idx2 >> 9, r = idx2 & 511, l = r >> 3, i = r & 7;
    int ct = fb / 7, ks = fb % 7;
    int k = ks*32 + ((l >> 4) << 3) + i;
    int col = ct*16 + (l & 15);
    if (k < 200 && col < 60) v = W[k*60 + col];
  } else {                                 // WQ1E (emb rows of Wq1, K=1024)
    int idx2 = id - 401408;
    int fb = idx2 >> 9, r = idx2 & 511, l = r >> 3, i = r & 7;
    int ks = fb / 13, ct = fb % 13;
    int k = ks*32 + ((l >> 4) << 3) + i;
    int col = ct*16 + (l & 15);
    if (col < 200) v = Wq1[(size_t)(200 + k)*200 + col];
  }
  ws[id] = f2bf(v);
}

// ---------------- P1: embq[t,b,:] = obs_embed[t,b,:] @ Wq1[200:,:] + bq1 ----
__global__ __launch_bounds__(512) void embq_kernel(
    const float* __restrict__ obs, const float* __restrict__ bq1,
    const u16* __restrict__ ws, float* __restrict__ embq) {
  __shared__ __align__(16) u16 Bl[6656];   // 13 frag-blocks x 1KB
  const int tid = threadIdx.x;
  const int w = tid >> 6, l = tid & 63;
  const int lr = l & 15, lk = (l >> 4) << 3, crw = (l >> 4) << 2;
  const size_t mb = (size_t)blockIdx.x * 128;
  const float* ap = obs + (mb + (size_t)w*16 + lr) * 1024 + lk;
  const u16* wsrc = ws + OFF_WQ1E;
  f32x4 zero = {0.f, 0.f, 0.f, 0.f};
  f32x4 acc[13];
  #pragma unroll
  for (int c = 0; c < 13; ++c) acc[c] = zero;
  for (int ks = 0; ks < 32; ++ks) {
    float4 a0 = *(const float4*)(ap);
    float4 a1 = *(const float4*)(ap + 4);
    ap += 32;
    __syncthreads();                        // prev-iter Bl reads done
    {
      const u16* src = wsrc + (size_t)ks * 6656;
      *(short8*)(Bl + tid*8) = *(const short8*)(src + tid*8);
      int idx = 512 + tid;
      if (idx < 832)
        *(short8*)(Bl + idx*8) = *(const short8*)(src + idx*8);
    }
    __syncthreads();
    short8 af;
    af[0]=(short)f2bf(a0.x); af[1]=(short)f2bf(a0.y); af[2]=(short)f2bf(a0.z); af[3]=(short)f2bf(a0.w);
    af[4]=(short)f2bf(a1.x); af[5]=(short)f2bf(a1.y); af[6]=(short)f2bf(a1.z); af[7]=(short)f2bf(a1.w);
    #pragma unroll
    for (int c = 0; c < 13; ++c) {
      short8 bf = *(const short8*)(Bl + c*512 + l*8);
      acc[c] = mfma16(af, bf, acc[c]);
    }
  }
  #pragma unroll
  for (int c = 0; c < 13; ++c) {
    int col = c*16 + lr;
    if (col < 200) {
      float bias = bq1[col];
      #pragma unroll
      for (int i = 0; i < 4; ++i) {
        size_t row = mb + (size_t)w*16 + crw + i;
        embq[row*200 + col] = acc[c][i] + bias;
      }
    }
  }
}

// ---------------- R: the 64-step rollout, 64 blocks x 16 batch rows ---------
__global__ __launch_bounds__(512) void rollout_kernel(
    const float* __restrict__ action, const float* __restrict__ prev_stoch,
    const float* __restrict__ prev_deter, const float* __restrict__ noise_prior,
    const float* __restrict__ noise_post, const float* __restrict__ Wri,
    const float* __restrict__ bri, const float* __restrict__ bih,
    const float* __restrict__ bhh, const float* __restrict__ bp1,
    const float* __restrict__ bp2, const float* __restrict__ bq2,
    const u16* __restrict__ ws, float* __restrict__ out) {
  float* o_pm  = out;
  float* o_ps  = out + TBN*30;
  float* o_pst = out + TBN*60;
  float* o_d1  = out + TBN*90;
  float* o_qm  = out + TBN*290;
  float* o_qs  = out + TBN*320;
  float* o_qst = out + TBN*350;
  float* o_d2  = out + TBN*380;          // holds embq until step t consumes it
  const float* embq = o_d2;

  __shared__ float s_stoch[16][30];
  __shared__ float s_deter[16][200];
  __shared__ __align__(16) u16 s_xbf[16][232];
  __shared__ __align__(16) u16 s_dbf[16][232];
  __shared__ __align__(16) u16 s_h1[16][232];
  __shared__ __align__(16) u16 s_h2[16][232];
  __shared__ float s_sr[16][200];
  __shared__ float s_sz[16][200];
  __shared__ float s_sn[16][200];
  __shared__ float s_hn[16][200];
  __shared__ float s_pml[16][30];
  __shared__ float s_psl[16][30];
  __shared__ float s_qml[16][30];
  __shared__ float s_qsl[16][30];

  const int tid = threadIdx.x;
  const int w = tid >> 6, l = tid & 63;
  const int lr = l & 15, lk = (l >> 4) << 3, crw = (l >> 4) << 2;
  const int rb = blockIdx.x * 16;

  for (int idx = tid; idx < 16*232; idx += 512) {
    (&s_xbf[0][0])[idx] = 0; (&s_dbf[0][0])[idx] = 0;
    (&s_h1[0][0])[idx] = 0;  (&s_h2[0][0])[idx] = 0;
  }
  for (int idx = tid; idx < 480; idx += 512) {
    int r = idx/30, c = idx%30;
    s_stoch[r][c] = prev_stoch[(rb + r)*30 + c];
  }
  for (int idx = tid; idx < 3200; idx += 512) {
    int r = idx/200, c = idx%200;
    float d = prev_deter[(rb + r)*200 + c];
    s_deter[r][c] = d;
    s_dbf[r][c] = f2bf(d);
  }
  __syncthreads();

  for (int t = 0; t < 64; ++t) {
    const size_t brow = (size_t)t*1024 + rb;
    // s0: x = elu([act, stoch] @ Wri + bri)   (K=36, VALU)
    for (int idx = tid; idx < 3200; idx += 512) {
      int r = idx/200, j = idx%200;
      const float* actp = action + (brow + r)*6;
      float a = bri[j];
      #pragma unroll
      for (int i = 0; i < 6; ++i) a += actp[i]*Wri[i*200 + j];
      for (int i = 0; i < 30; ++i) a += s_stoch[r][i]*Wri[(6+i)*200 + j];
      s_xbf[r][j] = f2bf(a > 0.f ? a : expm1f(a));
    }
    __syncthreads();
    // s1: gx = x@Wih, gh = deter@Whh  (39 units = 3 gates x 13 col-tiles)
    {
      f32x4 zero = {0.f,0.f,0.f,0.f};
      f32x4 aS[5], aH[5];
      #pragma unroll
      for (int uu = 0; uu < 5; ++uu) { aS[uu] = zero; aH[uu] = zero; }
      #pragma unroll
      for (int ks = 0; ks < 7; ++ks) {
        short8 ax = *(const short8*)&s_xbf[lr][ks*32 + lk];
        short8 ad = *(const short8*)&s_dbf[lr][ks*32 + lk];
        #pragma unroll
        for (int uu = 0; uu < 5; ++uu) {
          int u = w*5 + uu;
          if (u < 39) {
            int g = u/13, ct = u%13;
            size_t fo = (size_t)(((g*13 + ct)*7 + ks) << 9) + l*8;
            short8 bi = *(const short8*)(ws + OFF_WIH + fo);
            short8 bh = *(const short8*)(ws + OFF_WHH + fo);
            aS[uu] = mfma16(ax, bi, aS[uu]);
            aS[uu] = mfma16(ad, bh, aS[uu]);
            if (g == 2) aH[uu] = mfma16(ad, bh, aH[uu]);
          }
        }
      }
      #pragma unroll
      for (int uu = 0; uu < 5; ++uu) {
        int u = w*5 + uu;
        if (u < 39) {
          int g = u/13, ct = u%13;
          int col = ct*16 + lr;
          if (col < 200) {
            #pragma unroll
            for (int i = 0; i < 4; ++i) {
              int row = crw + i;
              if (g == 0)      s_sr[row][col] = aS[uu][i];
              else if (g == 1) s_sz[row][col] = aS[uu][i];
              else { s_sn[row][col] = aS[uu][i]; s_hn[row][col] = aH[uu][i]; }
            }
          }
        }
      }
    }
    __syncthreads();
    // s2: GRU combine -> deter_new
    for (int idx = tid; idx < 3200; idx += 512) {
      int r = idx/200, j = idx%200;
      float sr = s_sr[r][j] + bih[j]     + bhh[j];
      float sz = s_sz[r][j] + bih[200+j] + bhh[200+j];
      float sn = s_sn[r][j] + bih[400+j] + bhh[400+j];
      float hn = s_hn[r][j] + bhh[400+j];
      float rg = 1.f/(1.f + expf(-sr));
      float zg = 1.f/(1.f + expf(-sz));
      float ng = tanhf(sn + (rg - 1.f)*hn);   // = tanh(xn + r*hn)
      float dn = (1.f - zg)*ng + zg*s_deter[r][j];
      s_deter[r][j] = dn;
      s_dbf[r][j] = f2bf(dn);
      o_d1[(brow + r)*200 + j] = dn;
    }
    __syncthreads();
    // s3: h1 = elu(deter@Wp1+bp1), h2 = elu(deter@Wq1d + embq)
    {
      f32x4 zero = {0.f,0.f,0.f,0.f};
      f32x4 acc[4];
      #pragma unroll
      for (int uu = 0; uu < 4; ++uu) acc[uu] = zero;
      #pragma unroll
      for (int ks = 0; ks < 7; ++ks) {
        short8 ad = *(const short8*)&s_dbf[lr][ks*32 + lk];
        #pragma unroll
        for (int uu = 0; uu < 4; ++uu) {
          int u = w*4 + uu;
          if (u < 26) {
            int ct = (u < 13) ? u : u - 13;
            const u16* base = ws + ((u < 13) ? OFF_WP1 : OFF_WQ1D);
            short8 bf = *(const short8*)(base + ((ct*7 + ks) << 9) + l*8);
            acc[uu] = mfma16(ad, bf, acc[uu]);
          }
        }
      }
      #pragma unroll
      for (int uu = 0; uu < 4; ++uu) {
        int u = w*4 + uu;
        if (u < 26) {
          int ct = (u < 13) ? u : u - 13;
          int col = ct*16 + lr;
          if (col < 200) {
            #pragma unroll
            for (int i = 0; i < 4; ++i) {
              int row = crw + i;
              float v = acc[uu][i];
              if (u < 13) {
                v += bp1[col];
                s_h1[row][col] = f2bf(v > 0.f ? v : expm1f(v));
              } else {
                v += embq[(brow + row)*200 + col];  // includes bq1
                s_h2[row][col] = f2bf(v > 0.f ? v : expm1f(v));
              }
            }
          }
        }
      }
    }
    __syncthreads();
    // s4: pr = h1@Wp2+bp2, po = h2@Wq2+bq2 -> mean/std
    {
      f32x4 acc = {0.f,0.f,0.f,0.f};
      const int po = (w >= 4);
      const int ct = w & 3;
      const u16* sa = po ? &s_h2[0][0] : &s_h1[0][0];
      const u16* fbase = ws + (po ? OFF_WQ2 : OFF_WP2);
      #pragma unroll
      for (int ks = 0; ks < 7; ++ks) {
        short8 a = *(const short8*)(sa + lr*232 + ks*32 + lk);
        short8 b = *(const short8*)(fbase + ((ct*7 + ks) << 9) + l*8);
        acc = mfma16(a, b, acc);
      }
      const float* bias = po ? bq2 : bp2;
      int col = ct*16 + lr;
      if (col < 60) {
        float bv = bias[col];
        #pragma unroll
        for (int i = 0; i < 4; ++i) {
          int row = crw + i;
          float v = acc[i] + bv;
          size_t go = (brow + row)*30;
          if (col < 30) {
            if (po) { s_qml[row][col] = v; o_qm[go + col] = v; }
            else    { s_pml[row][col] = v; o_pm[go + col] = v; }
          } else {
            int c = col - 30;
            float s = (v > 20.f ? v : log1pf(expf(v))) + 0.1f;
            if (po) { s_qsl[row][c] = s; o_qs[go + c] = s; }
            else    { s_psl[row][c] = s; o_ps[go + c] = s; }
          }
        }
      }
    }
    __syncthreads();
    // s4b: stochastic samples + deter copy to slot 7 (frees embq[t] region)
    for (int idx = tid; idx < 480; idx += 512) {
      int r = idx/30, c = idx%30;
      size_t gi = (brow + r)*30 + c;
      float pst = s_pml[r][c] + s_psl[r][c]*noise_prior[gi];
      float qst = s_qml[r][c] + s_qsl[r][c]*noise_post[gi];
      o_pst[gi] = pst;
      o_qst[gi] = qst;
      s_stoch[r][c] = qst;
    }
    for (int idx = tid; idx < 3200; idx += 512) {
      int r = idx/200, j = idx%200;
      o_d2[(brow + r)*200 + j] = s_deter[r][j];
    }
    __syncthreads();
  }
}

extern "C" void kernel_launch(void* const* d_in, const int* in_sizes, int n_in,
                              void* d_out, int out_size, void* d_ws, size_t ws_size,
                              hipStream_t stream) {
  const float* obs  = (const float*)d_in[1];
  const float* act  = (const float*)d_in[2];
  const float* pst0 = (const float*)d_in[3];
  const float* pdt0 = (const float*)d_in[4];
  const float* npr  = (const float*)d_in[5];
  const float* npo  = (const float*)d_in[6];
  const float* Wri  = (const float*)d_in[7];
  const float* bri  = (const float*)d_in[8];
  const float* Wih  = (const float*)d_in[9];
  const float* bih  = (const float*)d_in[10];
  const float* Whh  = (const float*)d_in[11];
  const float* bhh  = (const float*)d_in[12];
  const float* Wp1  = (const float*)d_in[13];
  const float* bp1  = (const float*)d_in[14];
  const float* Wp2  = (const float*)d_in[15];
  const float* bp2  = (const float*)d_in[16];
  const float* Wq1  = (const float*)d_in[17];
  const float* bq1  = (const float*)d_in[18];
  const float* Wq2  = (const float*)d_in[19];
  const float* bq2  = (const float*)d_in[20];
  float* out = (float*)d_out;
  u16* ws = (u16*)d_ws;

  prep_frags<<<FRAG_TOTAL/512, 512, 0, stream>>>(Wih, Whh, Wp1, Wq1, Wp2, Wq2, ws);
  embq_kernel<<<512, 512, 0, stream>>>(obs, bq1, ws, out + TBN*380);
  rollout_kernel<<<64, 512, 0, stream>>>(act, pst0, pdt0, npr, npo, Wri, bri,
                                         bih, bhh, bp1, bp2, bq2, ws, out);
}

// Round 2
// 3481.553 us; speedup vs baseline: 1.4326x; 1.4326x over previous
//
#include <hip/hip_runtime.h>
#include <hip/hip_bf16.h>

typedef unsigned short u16;
typedef unsigned int u32;
typedef __attribute__((ext_vector_type(4))) float f32x4;
typedef __attribute__((ext_vector_type(8))) short short8;
typedef __attribute__((ext_vector_type(8))) __bf16 bf16x8;

#define TBN ((size_t)65536)  // T*B

// frag-layout offsets in u16 elements inside d_ws
#define OFF_WIH  0         // [3 gates][13 ct][7 ks][512]
#define OFF_WHH  139776
#define OFF_WP1  279552    // [13][7][512]
#define OFF_WQ1D 326144
#define OFF_WP2  372736    // [4][7][512]
#define OFF_WQ2  387072
#define OFF_WQ1E 401408    // [32 ks][13 ct][512]
#define FRAG_TOTAL 614400

__device__ __forceinline__ u16 f2bf(float f) {
  unsigned u = __builtin_bit_cast(unsigned, f);
  unsigned r = u + 0x7fffu + ((u >> 16) & 1u);
  return (u16)(r >> 16);
}
__device__ __forceinline__ float bf2f(u16 v) {
  unsigned u = ((unsigned)v) << 16;
  return __builtin_bit_cast(float, u);
}
__device__ __forceinline__ float fsig(float x) {
  return __builtin_amdgcn_rcpf(1.f + __expf(-x));
}
__device__ __forceinline__ float ftanh(float x) {
  return 1.f - 2.f * __builtin_amdgcn_rcpf(__expf(2.f * x) + 1.f);
}
__device__ __forceinline__ float fsoftplus(float x) {
  return (x > 20.f) ? x : __logf(1.f + __expf(x));
}
__device__ __forceinline__ float felu(float x) {
  return (x > 0.f) ? x : (__expf(x) - 1.f);
}

__device__ __forceinline__ f32x4 mfma16(short8 a, short8 b, f32x4 c) {
  return __builtin_amdgcn_mfma_f32_16x16x32_bf16(
      __builtin_bit_cast(bf16x8, a), __builtin_bit_cast(bf16x8, b), c, 0, 0, 0);
}

// ---------------- P0: pack weights into MFMA B-fragment order (bf16) --------
__global__ __launch_bounds__(512) void prep_frags(
    const float* __restrict__ Wih, const float* __restrict__ Whh,
    const float* __restrict__ Wp1, const float* __restrict__ Wq1,
    const float* __restrict__ Wp2, const float* __restrict__ Wq2,
    u16* __restrict__ ws) {
  int id = blockIdx.x * 512 + threadIdx.x;
  float v = 0.f;
  if (id < 279552) {                       // WIH / WHH  (K=200, N=3x200)
    const float* W = (id < 139776) ? Wih : Whh;
    int idx2 = (id < 139776) ? id : id - 139776;
    int fb = idx2 >> 9, r = idx2 & 511, l = r >> 3, i = r & 7;
    int g = fb / 91, rem = fb % 91, ct = rem / 7, ks = rem % 7;
    int k = ks*32 + ((l >> 4) << 3) + i;
    int col = ct*16 + (l & 15);
    if (k < 200 && col < 200) v = W[k*600 + g*200 + col];
  } else if (id < 372736) {                // WP1 / WQ1D  (K=200, N=200)
    const float* W = (id < 326144) ? Wp1 : Wq1;
    int idx2 = (id < 326144) ? id - 279552 : id - 326144;
    int fb = idx2 >> 9, r = idx2 & 511, l = r >> 3, i = r & 7;
    int ct = fb / 7, ks = fb % 7;
    int k = ks*32 + ((l >> 4) << 3) + i;
    int col = ct*16 + (l & 15);
    if (k < 200 && col < 200) v = W[k*200 + col];
  } else if (id < 401408) {                // WP2 / WQ2  (K=200, N=60)
    const float* W = (id < 387072) ? Wp2 : Wq2;
    int idx2 = (id < 387072) ? id - 372736 : id - 387072;
    int fb = idx2 >> 9, r = idx2 & 511, l = r >> 3, i = r & 7;
    int ct = fb / 7, ks = fb % 7;
    int k = ks*32 + ((l >> 4) << 3) + i;
    int col = ct*16 + (l & 15);
    if (k < 200 && col < 60) v = W[k*60 + col];
  } else {                                 // WQ1E (emb rows of Wq1, K=1024)
    int idx2 = id - 401408;
    int fb = idx2 >> 9, r = idx2 & 511, l = r >> 3, i = r & 7;
    int ks = fb / 13, ct = fb % 13;
    int k = ks*32 + ((l >> 4) << 3) + i;
    int col = ct*16 + (l & 15);
    if (col < 200) v = Wq1[(size_t)(200 + k)*200 + col];
  }
  ws[id] = f2bf(v);
}

// ---------------- P1: embq (bf16) = obs_embed @ Wq1[200:,:] + bq1 -----------
// Stored packed-u16 inside the o_d2 output region: row r occupies u16 slots
// [r*400, r*400+200) (first half of the f32 row bytes). Block-private rows in
// the rollout make the later overwrite race-free.
__global__ __launch_bounds__(512) void embq_kernel(
    const float* __restrict__ obs, const float* __restrict__ bq1,
    const u16* __restrict__ ws, u16* __restrict__ embq) {
  __shared__ __align__(16) u16 Bl[6656];   // 13 frag-blocks x 1KB
  const int tid = threadIdx.x;
  const int w = tid >> 6, l = tid & 63;
  const int lr = l & 15, lk = (l >> 4) << 3, crw = (l >> 4) << 2;
  const size_t mb = (size_t)blockIdx.x * 128;
  const float* ap = obs + (mb + (size_t)w*16 + lr) * 1024 + lk;
  const u16* wsrc = ws + OFF_WQ1E;
  f32x4 zero = {0.f, 0.f, 0.f, 0.f};
  f32x4 acc[13];
  #pragma unroll
  for (int c = 0; c < 13; ++c) acc[c] = zero;
  for (int ks = 0; ks < 32; ++ks) {
    float4 a0 = *(const float4*)(ap);
    float4 a1 = *(const float4*)(ap + 4);
    ap += 32;
    __syncthreads();                        // prev-iter Bl reads done
    {
      const u16* src = wsrc + (size_t)ks * 6656;
      *(short8*)(Bl + tid*8) = *(const short8*)(src + tid*8);
      int idx = 512 + tid;
      if (idx < 832)
        *(short8*)(Bl + idx*8) = *(const short8*)(src + idx*8);
    }
    __syncthreads();
    short8 af;
    af[0]=(short)f2bf(a0.x); af[1]=(short)f2bf(a0.y); af[2]=(short)f2bf(a0.z); af[3]=(short)f2bf(a0.w);
    af[4]=(short)f2bf(a1.x); af[5]=(short)f2bf(a1.y); af[6]=(short)f2bf(a1.z); af[7]=(short)f2bf(a1.w);
    #pragma unroll
    for (int c = 0; c < 13; ++c) {
      short8 bf = *(const short8*)(Bl + c*512 + l*8);
      acc[c] = mfma16(af, bf, acc[c]);
    }
  }
  #pragma unroll
  for (int c = 0; c < 13; ++c) {
    int col = c*16 + lr;
    if (col < 200) {
      float bias = bq1[col];
      #pragma unroll
      for (int i = 0; i < 4; ++i) {
        size_t row = mb + (size_t)w*16 + crw + i;
        embq[row*400 + col] = f2bf(acc[c][i] + bias);
      }
    }
  }
}

// ---------------- R: the 64-step rollout, 64 blocks x 16 batch rows ---------
__global__ __launch_bounds__(512, 1) void rollout_kernel(
    const float* __restrict__ action, const float* __restrict__ prev_stoch,
    const float* __restrict__ prev_deter, const float* __restrict__ noise_post,
    const float* __restrict__ Wri, const float* __restrict__ bri,
    const float* __restrict__ bih, const float* __restrict__ bhh,
    const float* __restrict__ bq2, const u16* __restrict__ ws,
    float* __restrict__ out) {
  float* o_d1  = out + TBN*90;
  float* o_qm  = out + TBN*290;
  float* o_qs  = out + TBN*320;
  float* o_qst = out + TBN*350;
  float* o_d2  = out + TBN*380;          // lower bytes of each row hold embq(t) bf16
  const u32* embq32 = (const u32*)o_d2;

  __shared__ float s_wri[7200];                       // Wri resident (f32)
  __shared__ float s_bih[600], s_bhh[600], s_bri[200], s_bq2[60];
  __shared__ float s_stoch[16][30];
  __shared__ float s_deter[16][200];
  __shared__ __align__(16) u16 s_xbf[16][232];
  __shared__ __align__(16) u16 s_dbf[16][232];
  __shared__ __align__(16) u16 s_h2[16][232];
  __shared__ __align__(4)  u16 s_embq[3200];          // [16][200]
  __shared__ float s_sr[16][200];
  __shared__ float s_sz[16][200];
  __shared__ float s_sn[16][200];
  __shared__ float s_hn[16][200];
  __shared__ float s_qml[16][30];
  __shared__ float s_qsl[16][30];

  const int tid = threadIdx.x;
  const int w = tid >> 6, l = tid & 63;
  const int lr = l & 15, lk = (l >> 4) << 3, crw = (l >> 4) << 2;
  const int rb = blockIdx.x * 16;
  const f32x4 fzero = {0.f, 0.f, 0.f, 0.f};

  // ---- one-time init ----
  for (int idx = tid; idx < 16*232; idx += 512) {
    (&s_xbf[0][0])[idx] = 0; (&s_dbf[0][0])[idx] = 0; (&s_h2[0][0])[idx] = 0;
  }
  for (int idx = tid; idx < 7200; idx += 512) s_wri[idx] = Wri[idx];
  for (int idx = tid; idx < 600; idx += 512)  { s_bih[idx] = bih[idx]; s_bhh[idx] = bhh[idx]; }
  if (tid < 200) s_bri[tid] = bri[tid];
  if (tid < 60)  s_bq2[tid] = bq2[tid];
  for (int idx = tid; idx < 480; idx += 512) {
    int r = idx/30, c = idx%30;
    s_stoch[r][c] = prev_stoch[(rb + r)*30 + c];
  }
  for (int idx = tid; idx < 3200; idx += 512) {
    int r = idx/200, c = idx%200;
    float d = prev_deter[(rb + r)*200 + c];
    s_deter[r][c] = d;
    s_dbf[r][c] = f2bf(d);
  }
  __syncthreads();

  for (int t = 0; t < 64; ++t) {
    const size_t brow = (size_t)t*1024 + rb;

    // ---- A: embq(t) prefetch to LDS + s0 (x = elu([act,stoch]@Wri+bri)) ----
    {
      u32* sdst = (u32*)s_embq;
      for (int idx = tid; idx < 1600; idx += 512) {
        int r = idx / 100, c = idx - r*100;
        sdst[r*100 + c] = embq32[(size_t)(brow + r)*200 + c];
      }
      for (int idx = tid; idx < 3200; idx += 512) {
        int r = idx/200, j = idx - r*200;
        const float* actp = action + (brow + r)*6;
        float a = s_bri[j];
        #pragma unroll
        for (int i = 0; i < 6; ++i) a += actp[i]*s_wri[i*200 + j];
        #pragma unroll 6
        for (int i = 0; i < 30; ++i) a += s_stoch[r][i]*s_wri[(6+i)*200 + j];
        s_xbf[r][j] = f2bf(felu(a));
      }
    }
    __syncthreads();

    // ---- B: gates. gx = x@Wih (all 3), gh = deter@Whh (r,z full; n separate)
    {
      int gArr[5];
      u32 offI[5], offH[5];
      #pragma unroll
      for (int uu = 0; uu < 5; ++uu) {
        int u = w*5 + uu;
        int uc = (u < 39) ? u : 38;
        int g = uc/13, ct = uc%13;
        gArr[uu] = (u < 39) ? g : -1;
        offI[uu] = (u32)(OFF_WIH + (((g*13 + ct)*7) << 9) + l*8);
        offH[uu] = offI[uu] + (u32)(OFF_WHH - OFF_WIH);
      }
      f32x4 aS[5], aH[5];
      #pragma unroll
      for (int uu = 0; uu < 5; ++uu) { aS[uu] = fzero; aH[uu] = fzero; }
      short8 bi[2][5], bh[2][5];
      #pragma unroll
      for (int uu = 0; uu < 5; ++uu) {
        bi[0][uu] = *(const short8*)(ws + offI[uu]);
        bh[0][uu] = *(const short8*)(ws + offH[uu]);
      }
      #pragma unroll
      for (int ks = 0; ks < 7; ++ks) {
        const int cur = ks & 1, nxt = cur ^ 1;
        if (ks < 6) {
          #pragma unroll
          for (int uu = 0; uu < 5; ++uu) {
            bi[nxt][uu] = *(const short8*)(ws + offI[uu] + (ks+1)*512);
            bh[nxt][uu] = *(const short8*)(ws + offH[uu] + (ks+1)*512);
          }
        }
        short8 ax = *(const short8*)&s_xbf[lr][ks*32 + lk];
        short8 ad = *(const short8*)&s_dbf[lr][ks*32 + lk];
        #pragma unroll
        for (int uu = 0; uu < 5; ++uu) {
          if (gArr[uu] >= 0) {
            aS[uu] = mfma16(ax, bi[cur][uu], aS[uu]);
            if (gArr[uu] < 2) aS[uu] = mfma16(ad, bh[cur][uu], aS[uu]);
            else              aH[uu] = mfma16(ad, bh[cur][uu], aH[uu]);
          }
        }
      }
      #pragma unroll
      for (int uu = 0; uu < 5; ++uu) {
        int u = w*5 + uu;
        if (u < 39) {
          int g = u/13, ct = u%13;
          int col = ct*16 + lr;
          if (col < 200) {
            #pragma unroll
            for (int i = 0; i < 4; ++i) {
              int row = crw + i;
              if (g == 0)      s_sr[row][col] = aS[uu][i];
              else if (g == 1) s_sz[row][col] = aS[uu][i];
              else { s_sn[row][col] = aS[uu][i]; s_hn[row][col] = aH[uu][i]; }
            }
          }
        }
      }
    }
    __syncthreads();

    // ---- C: GRU combine -> deter_new ----
    for (int idx = tid; idx < 3200; idx += 512) {
      int r = idx/200, j = idx - r*200;
      float sr = s_sr[r][j] + s_bih[j]     + s_bhh[j];
      float sz = s_sz[r][j] + s_bih[200+j] + s_bhh[200+j];
      float xn = s_sn[r][j] + s_bih[400+j];
      float hn = s_hn[r][j] + s_bhh[400+j];
      float rg = fsig(sr);
      float zg = fsig(sz);
      float ng = ftanh(xn + rg*hn);
      float dn = (1.f - zg)*ng + zg*s_deter[r][j];
      s_deter[r][j] = dn;
      s_dbf[r][j] = f2bf(dn);
      o_d1[(brow + r)*200 + j] = dn;
    }
    __syncthreads();

    // ---- D: h2 = elu(deter@Wq1d + embq) ----
    {
      const int u0 = w;                        // units 0..7
      const int u1 = (w < 5) ? (8 + w) : 12;   // units 8..12 (w<5)
      const u32 off0 = (u32)(OFF_WQ1D + ((u0*7) << 9) + l*8);
      const u32 off1 = (u32)(OFF_WQ1D + ((u1*7) << 9) + l*8);
      f32x4 aA = fzero, aB = fzero;
      short8 c0[2], c1[2];
      c0[0] = *(const short8*)(ws + off0);
      c1[0] = *(const short8*)(ws + off1);
      #pragma unroll
      for (int ks = 0; ks < 7; ++ks) {
        const int cur = ks & 1, nxt = cur ^ 1;
        if (ks < 6) {
          c0[nxt] = *(const short8*)(ws + off0 + (ks+1)*512);
          c1[nxt] = *(const short8*)(ws + off1 + (ks+1)*512);
        }
        short8 ad = *(const short8*)&s_dbf[lr][ks*32 + lk];
        aA = mfma16(ad, c0[cur], aA);
        if (w < 5) aB = mfma16(ad, c1[cur], aB);
      }
      {
        int col = u0*16 + lr;                  // < 128, always valid
        #pragma unroll
        for (int i = 0; i < 4; ++i) {
          int row = crw + i;
          float v = aA[i] + bf2f(s_embq[row*200 + col]);
          s_h2[row][col] = f2bf(felu(v));
        }
      }
      if (w < 5) {
        int col = u1*16 + lr;
        if (col < 200) {
          #pragma unroll
          for (int i = 0; i < 4; ++i) {
            int row = crw + i;
            float v = aB[i] + bf2f(s_embq[row*200 + col]);
            s_h2[row][col] = f2bf(felu(v));
          }
        }
      }
    }
    __syncthreads();

    // ---- E1: posterior head (waves 0-3) ; o_d2 deter write (waves 4-7) ----
    if (w < 4) {
      const u32 off = (u32)(OFF_WQ2 + ((w*7) << 9) + l*8);
      f32x4 acc = fzero;
      short8 cb[2];
      cb[0] = *(const short8*)(ws + off);
      #pragma unroll
      for (int ks = 0; ks < 7; ++ks) {
        const int cur = ks & 1, nxt = cur ^ 1;
        if (ks < 6) cb[nxt] = *(const short8*)(ws + off + (ks+1)*512);
        short8 a = *(const short8*)&s_h2[lr][ks*32 + lk];
        acc = mfma16(a, cb[cur], acc);
      }
      int col = w*16 + lr;
      if (col < 60) {
        float bv = s_bq2[col];
        #pragma unroll
        for (int i = 0; i < 4; ++i) {
          int row = crw + i;
          float v = acc[i] + bv;
          size_t go = (brow + row)*30;
          if (col < 30) { s_qml[row][col] = v; o_qm[go + col] = v; }
          else {
            int c = col - 30;
            float s = fsoftplus(v) + 0.1f;
            s_qsl[row][c] = s; o_qs[go + c] = s;
          }
        }
      }
    } else {
      for (int idx = tid - 256; idx < 3200; idx += 256) {
        int r = idx/200, j = idx - r*200;
        o_d2[(brow + r)*200 + j] = s_deter[r][j];
      }
    }
    __syncthreads();

    // ---- E2: posterior sample -> q_stoch (feeds next step) ----
    for (int idx = tid; idx < 480; idx += 512) {
      int r = idx/30, c = idx - r*30;
      size_t gi = (brow + r)*30 + c;
      float qst = s_qml[r][c] + s_qsl[r][c]*noise_post[gi];
      o_qst[gi] = qst;
      s_stoch[r][c] = qst;
    }
    __syncthreads();
  }
}

// ---------------- P2: prior head, fully parallel over all (t,b) rows --------
__global__ __launch_bounds__(512, 2) void prior_kernel(
    const float* __restrict__ deter, const float* __restrict__ noise_prior,
    const float* __restrict__ bp1, const float* __restrict__ bp2,
    const u16* __restrict__ ws, float* __restrict__ out) {
  float* o_pm  = out;
  float* o_ps  = out + TBN*30;
  float* o_pst = out + TBN*60;

  __shared__ __align__(16) u16 s_h1[8][16][232];
  __shared__ float s_pm[8][16][30];
  __shared__ float s_ps[8][16][30];

  const int tid = threadIdx.x;
  const int w = tid >> 6, l = tid & 63;
  const int lr = l & 15, lk = (l >> 4) << 3, crw = (l >> 4) << 2;
  const size_t row0 = (size_t)blockIdx.x*128 + w*16;
  const f32x4 fzero = {0.f, 0.f, 0.f, 0.f};

  for (int idx = tid; idx < 8*16*232/2; idx += 512) ((u32*)&s_h1[0][0][0])[idx] = 0;
  __syncthreads();

  // A-fragments of deter (bf16)
  short8 adf[7];
  const float* drow = deter + (row0 + lr)*200;
  #pragma unroll
  for (int ks = 0; ks < 7; ++ks) {
    short8 tf;
    #pragma unroll
    for (int i = 0; i < 8; ++i) {
      int k = ks*32 + lk + i;
      float v = (k < 200) ? drow[k] : 0.f;
      tf[i] = (short)f2bf(v);
    }
    adf[ks] = tf;
  }
  // h1 = elu(deter@Wp1 + bp1)
  #pragma unroll
  for (int u = 0; u < 13; ++u) {
    f32x4 acc = fzero;
    #pragma unroll
    for (int ks = 0; ks < 7; ++ks) {
      short8 b = *(const short8*)(ws + OFF_WP1 + ((u*7 + ks) << 9) + l*8);
      acc = mfma16(adf[ks], b, acc);
    }
    int col = u*16 + lr;
    if (col < 200) {
      float bb = bp1[col];
      #pragma unroll
      for (int i = 0; i < 4; ++i)
        s_h1[w][crw + i][col] = f2bf(felu(acc[i] + bb));
    }
  }
  __syncthreads();
  // pr = h1@Wp2 + bp2
  short8 ahf[7];
  #pragma unroll
  for (int ks = 0; ks < 7; ++ks)
    ahf[ks] = *(const short8*)&s_h1[w][lr][ks*32 + lk];
  #pragma unroll
  for (int ct = 0; ct < 4; ++ct) {
    f32x4 acc = fzero;
    #pragma unroll
    for (int ks = 0; ks < 7; ++ks) {
      short8 b = *(const short8*)(ws + OFF_WP2 + ((ct*7 + ks) << 9) + l*8);
      acc = mfma16(ahf[ks], b, acc);
    }
    int col = ct*16 + lr;
    if (col < 60) {
      float bb = bp2[col];
      #pragma unroll
      for (int i = 0; i < 4; ++i) {
        int r = crw + i;
        float v = acc[i] + bb;
        size_t go = (row0 + r)*30;
        if (col < 30) { s_pm[w][r][col] = v; o_pm[go + col] = v; }
        else {
          int c = col - 30;
          float s = fsoftplus(v) + 0.1f;
          s_ps[w][r][c] = s; o_ps[go + c] = s;
        }
      }
    }
  }
  __syncthreads();
  for (int idx = tid; idx < 3840; idx += 512) {
    int w2 = idx/480, rem = idx - w2*480;
    int r = rem/30, c = rem - r*30;
    size_t grow = (size_t)blockIdx.x*128 + w2*16 + r;
    float pst = s_pm[w2][r][c] + s_ps[w2][r][c]*noise_prior[grow*30 + c];
    o_pst[grow*30 + c] = pst;
  }
}

extern "C" void kernel_launch(void* const* d_in, const int* in_sizes, int n_in,
                              void* d_out, int out_size, void* d_ws, size_t ws_size,
                              hipStream_t stream) {
  const float* obs  = (const float*)d_in[1];
  const float* act  = (const float*)d_in[2];
  const float* pst0 = (const float*)d_in[3];
  const float* pdt0 = (const float*)d_in[4];
  const float* npr  = (const float*)d_in[5];
  const float* npo  = (const float*)d_in[6];
  const float* Wri  = (const float*)d_in[7];
  const float* bri  = (const float*)d_in[8];
  const float* Wih  = (const float*)d_in[9];
  const float* bih  = (const float*)d_in[10];
  const float* Whh  = (const float*)d_in[11];
  const float* bhh  = (const float*)d_in[12];
  const float* Wp1  = (const float*)d_in[13];
  const float* bp1  = (const float*)d_in[14];
  const float* Wp2  = (const float*)d_in[15];
  const float* bp2  = (const float*)d_in[16];
  const float* Wq1  = (const float*)d_in[17];
  const float* bq1  = (const float*)d_in[18];
  const float* Wq2  = (const float*)d_in[19];
  const float* bq2  = (const float*)d_in[20];
  float* out = (float*)d_out;
  u16* ws = (u16*)d_ws;

  prep_frags<<<FRAG_TOTAL/512, 512, 0, stream>>>(Wih, Whh, Wp1, Wq1, Wp2, Wq2, ws);
  embq_kernel<<<512, 512, 0, stream>>>(obs, bq1, ws, (u16*)(out + TBN*380));
  rollout_kernel<<<64, 512, 0, stream>>>(act, pst0, pdt0, npo, Wri, bri,
                                         bih, bhh, bq2, ws, out);
  prior_kernel<<<512, 512, 0, stream>>>(out + TBN*90, npr, bp1, bp2, ws, out);
}